// Round 5
// baseline (888.336 us; speedup 1.0000x reference)
//
#include <hip/hip_runtime.h>
#include <hip/hip_bf16.h>

typedef float f32x4 __attribute__((ext_vector_type(4)));
typedef int i32x4v __attribute__((ext_vector_type(4)));
typedef int i32x8v __attribute__((ext_vector_type(8)));

#define IGNORE_INDEX (-100)
#define N_ROWS 4096
#define H_DIM  1024
#define V_DIM  32000

#define BM 128
#define BN 128
#define BK 128                 /* fp8 elements = bytes */
#define CT_NUM (V_DIM / BN)    /* 250 */
#define RT_NUM (N_ROWS / BM)   /* 32 */
#define SCALE1 0x7f7f7f7f      /* 4x e8m0 = 127 -> x1.0 */

// ---------- fused prep: cast x -> fp8 (blocks < XB8) + transpose-cast w ----------
// transpose tile 128(k) x 64(v): 256B contiguous per row-visit on the read
// side, 64B-contiguous-per-4-lanes on the write side (full 128B line per row
// across the two write insts).
#define XB8 (N_ROWS * H_DIM / (256 * 16))  /* 1024 */
__global__ __launch_bounds__(256) void k_prep(const float* __restrict__ x,
                                              const float* __restrict__ w,
                                              unsigned char* __restrict__ x8,
                                              unsigned char* __restrict__ wT8) {
  __shared__ float tile[128][65];
  const int t = threadIdx.x;
  if (blockIdx.x < XB8) {
    size_t i = ((size_t)blockIdx.x * 256 + t) * 16;
    const float4* xp = (const float4*)(x + i);
    float4 f0 = xp[0], f1 = xp[1], f2 = xp[2], f3 = xp[3];
    int4 o;
    int r;
    r = __builtin_amdgcn_cvt_pk_fp8_f32(f0.x, f0.y, 0, false);
    r = __builtin_amdgcn_cvt_pk_fp8_f32(f0.z, f0.w, r, true);
    o.x = r;
    r = __builtin_amdgcn_cvt_pk_fp8_f32(f1.x, f1.y, 0, false);
    r = __builtin_amdgcn_cvt_pk_fp8_f32(f1.z, f1.w, r, true);
    o.y = r;
    r = __builtin_amdgcn_cvt_pk_fp8_f32(f2.x, f2.y, 0, false);
    r = __builtin_amdgcn_cvt_pk_fp8_f32(f2.z, f2.w, r, true);
    o.z = r;
    r = __builtin_amdgcn_cvt_pk_fp8_f32(f3.x, f3.y, 0, false);
    r = __builtin_amdgcn_cvt_pk_fp8_f32(f3.z, f3.w, r, true);
    o.w = r;
    *(int4*)(x8 + i) = o;
    return;
  }
  const int b = blockIdx.x - XB8;
  const int v0 = (b % (V_DIM / 64)) * 64;
  const int k0 = (b / (V_DIM / 64)) * 128;
  {
    const int vq = t & 15;    // float4 index (16 x 4 = 64 floats/row)
    const int kr = t >> 4;    // 0..15
#pragma unroll
    for (int p = 0; p < 128; p += 16) {
      float4 v = *(const float4*)(w + (size_t)(k0 + kr + p) * V_DIM + v0 + vq * 4);
      tile[kr + p][vq * 4 + 0] = v.x;
      tile[kr + p][vq * 4 + 1] = v.y;
      tile[kr + p][vq * 4 + 2] = v.z;
      tile[kr + p][vq * 4 + 3] = v.w;
    }
  }
  __syncthreads();
  {
    const int vr = t >> 2;    // 0..63
    const int kq2 = t & 3;
#pragma unroll
    for (int h = 0; h < 2; ++h) {
      const int d4 = kq2 + h * 4;   // int4 index within 128B k-run
      int4 o;
      int r;
#pragma unroll
      for (int d = 0; d < 4; ++d) {
        r = __builtin_amdgcn_cvt_pk_fp8_f32(tile[d4 * 16 + d * 4 + 0][vr],
                                            tile[d4 * 16 + d * 4 + 1][vr], 0, false);
        r = __builtin_amdgcn_cvt_pk_fp8_f32(tile[d4 * 16 + d * 4 + 2][vr],
                                            tile[d4 * 16 + d * 4 + 3][vr], r, true);
        ((int*)&o)[d] = r;
      }
      *(int4*)(wT8 + (size_t)(v0 + vr) * H_DIM + k0 + d4 * 16) = o;
    }
  }
}

// ------------- fused MX-fp8 GEMM tile + per-row max/sumexp partials -------------
// LDS layout per operand (16KB): 16B slot s holds (row = s>>3, chunk c where
// chunk-position (s&7) = c ^ (row&7)).  Epilogue max/sum buffers UNION into
// sA (dead after K-loop) -> LDS exactly 32768 B -> 5 blocks/CU.
__global__ __launch_bounds__(256, 5) void k_gemm_lse(const unsigned char* __restrict__ A,
                                                     const unsigned char* __restrict__ Bt,
                                                     float* __restrict__ m_part,
                                                     float* __restrict__ s_part) {
  __shared__ __align__(16) unsigned char sA[BM * BK];
  __shared__ __align__(16) unsigned char sB[BN * BK];
  float* maxbuf = (float*)sA;            // [BM][2], alias: sA dead post-loop
  float* sumbuf = (float*)(sA + 2048);   // [BM][2]

  const int tid = threadIdx.x;
  const int rt = blockIdx.x;   // fast dim -> per-XCD A stays hot
  const int ct = blockIdx.y;
  const int m0 = rt * BM;
  const int n0 = ct * BN;

  const int w = tid >> 6;
  const int l = tid & 63;
  const int wr = w >> 1, wc = w & 1;
  const int quad = l >> 4, lc = l & 15;

  f32x4 acc[4][4];
#pragma unroll
  for (int i = 0; i < 4; ++i)
#pragma unroll
    for (int j = 0; j < 4; ++j)
      acc[i][j] = (f32x4){0.f, 0.f, 0.f, 0.f};

  // staging addresses (issue i adds 32 rows / 4096 LDS bytes)
  const int srow = tid >> 3;                               // 0..31
  const int scol = ((tid & 7) ^ ((tid >> 3) & 7)) * 16;    // swizzled 16B chunk
  const unsigned char* ga = A + (size_t)(m0 + srow) * H_DIM + scol;
  const unsigned char* gb = Bt + (size_t)(n0 + srow) * H_DIM + scol;
  unsigned char* da = sA + tid * 16;
  unsigned char* db = sB + tid * 16;

  // fragment read offsets
  const int base_r = lc * 128;
  const int sw0 = ((quad * 2) ^ (lc & 7)) * 16;
  const int sw1 = ((quad * 2 + 1) ^ (lc & 7)) * 16;

  for (int kt = 0; kt < H_DIM / BK; ++kt) {
    __syncthreads();  // previous iter's ds_reads done before overwrite
#pragma unroll
    for (int i = 0; i < 4; ++i) {
      __builtin_amdgcn_global_load_lds(
          (const __attribute__((address_space(1))) void*)(ga + (size_t)i * 32 * H_DIM),
          (__attribute__((address_space(3))) void*)(da + i * 4096), 16, 0, 0);
      __builtin_amdgcn_global_load_lds(
          (const __attribute__((address_space(1))) void*)(gb + (size_t)i * 32 * H_DIM),
          (__attribute__((address_space(3))) void*)(db + i * 4096), 16, 0, 0);
    }
    ga += BK; gb += BK;
    __syncthreads();  // drains vmcnt for all waves

    i32x8v a_frag[4], b_frag[4];
#pragma unroll
    for (int i = 0; i < 4; ++i) {
      const unsigned char* p = sA + (wr * 4 + i) * 2048 + base_r;
      i32x4v lo = *(const i32x4v*)(p + sw0);
      i32x4v hi = *(const i32x4v*)(p + sw1);
      a_frag[i] = __builtin_shufflevector(lo, hi, 0, 1, 2, 3, 4, 5, 6, 7);
    }
#pragma unroll
    for (int j = 0; j < 4; ++j) {
      const unsigned char* p = sB + (wc * 4 + j) * 2048 + base_r;
      i32x4v lo = *(const i32x4v*)(p + sw0);
      i32x4v hi = *(const i32x4v*)(p + sw1);
      b_frag[j] = __builtin_shufflevector(lo, hi, 0, 1, 2, 3, 4, 5, 6, 7);
    }
#pragma unroll
    for (int i = 0; i < 4; ++i)
#pragma unroll
      for (int j = 0; j < 4; ++j)
        acc[i][j] = __builtin_amdgcn_mfma_scale_f32_16x16x128_f8f6f4(
            a_frag[i], b_frag[j], acc[i][j], 0, 0, 0, SCALE1, 0, SCALE1);
  }

  // C/D layout (shape-determined): col = lane&15, row = quad*4 + reg.
  float rmax[4][4];
#pragma unroll
  for (int i = 0; i < 4; ++i)
#pragma unroll
    for (int r = 0; r < 4; ++r) {
      float mx = fmaxf(fmaxf(acc[i][0][r], acc[i][1][r]),
                       fmaxf(acc[i][2][r], acc[i][3][r]));
#pragma unroll
      for (int off = 1; off < 16; off <<= 1)
        mx = fmaxf(mx, __shfl_xor(mx, off, 64));
      rmax[i][r] = mx;
    }
  __syncthreads();  // all waves past final ds_reads; sA now safe to alias
  if (lc == 0) {
#pragma unroll
    for (int i = 0; i < 4; ++i)
#pragma unroll
      for (int r = 0; r < 4; ++r)
        maxbuf[(wr * 64 + i * 16 + quad * 4 + r) * 2 + wc] = rmax[i][r];
  }
  __syncthreads();
  float rowmax[4][4];
#pragma unroll
  for (int i = 0; i < 4; ++i)
#pragma unroll
    for (int r = 0; r < 4; ++r) {
      int row = wr * 64 + i * 16 + quad * 4 + r;
      rowmax[i][r] = fmaxf(maxbuf[row * 2], maxbuf[row * 2 + 1]);
    }
#pragma unroll
  for (int i = 0; i < 4; ++i)
#pragma unroll
    for (int r = 0; r < 4; ++r) {
      float s = __expf(acc[i][0][r] - rowmax[i][r]) + __expf(acc[i][1][r] - rowmax[i][r]) +
                __expf(acc[i][2][r] - rowmax[i][r]) + __expf(acc[i][3][r] - rowmax[i][r]);
#pragma unroll
      for (int off = 1; off < 16; off <<= 1)
        s += __shfl_xor(s, off, 64);
      if (lc == 0) sumbuf[(wr * 64 + i * 16 + quad * 4 + r) * 2 + wc] = s;
    }
  __syncthreads();
  if (wc == 0 && lc == 0) {
#pragma unroll
    for (int i = 0; i < 4; ++i)
#pragma unroll
      for (int r = 0; r < 4; ++r) {
        int row = wr * 64 + i * 16 + quad * 4 + r;
        size_t idx = (size_t)(m0 + row) * CT_NUM + ct;
        m_part[idx] = rowmax[i][r];
        s_part[idx] = sumbuf[row * 2] + sumbuf[row * 2 + 1];
      }
  }
}

// ------------- combine partials + target logit -> per-block partial sums ----
__global__ __launch_bounds__(256) void k_combine(const float* __restrict__ x,
                                                 const unsigned char* __restrict__ wT8,
                                                 const int* __restrict__ target,
                                                 const float* __restrict__ m_part,
                                                 const float* __restrict__ s_part,
                                                 float* __restrict__ blk_part) {
  __shared__ float red[8];
  const int wv = threadIdx.x >> 6;
  const int row = blockIdx.x * 4 + wv;  // one wave per row
  const int l = threadIdx.x & 63;
  float m = -INFINITY, s = 0.f;
  for (int ctb = l; ctb < CT_NUM; ctb += 64) {
    float mj = m_part[(size_t)row * CT_NUM + ctb];
    float sj = s_part[(size_t)row * CT_NUM + ctb];
    float M = fmaxf(m, mj);
    s = s * __expf(m - M) + sj * __expf(mj - M);
    m = M;
  }
#pragma unroll
  for (int off = 1; off < 64; off <<= 1) {
    float mo = __shfl_xor(m, off, 64);
    float so = __shfl_xor(s, off, 64);
    float M = fmaxf(m, mo);
    s = s * __expf(m - M) + so * __expf(mo - M);
    m = M;
  }
  float lse = m + logf(s);
  int tgt = target[row];
  bool valid = (tgt != IGNORE_INDEX);
  int st = valid ? tgt : 0;
  // target logit: x[row] fp32 . wT8[st] fp8 (16 bytes per lane)
  const float* xr = x + (size_t)row * H_DIM + l * 16;
  int4 wv4 = *(const int4*)(wT8 + (size_t)st * H_DIM + l * 16);
  float t = 0.f;
#define ACC_DW(dw, base)                                              \
  t += xr[base + 0] * __builtin_amdgcn_cvt_f32_fp8(dw, 0);            \
  t += xr[base + 1] * __builtin_amdgcn_cvt_f32_fp8(dw, 1);            \
  t += xr[base + 2] * __builtin_amdgcn_cvt_f32_fp8(dw, 2);            \
  t += xr[base + 3] * __builtin_amdgcn_cvt_f32_fp8(dw, 3);
  ACC_DW(wv4.x, 0)
  ACC_DW(wv4.y, 4)
  ACC_DW(wv4.z, 8)
  ACC_DW(wv4.w, 12)
#undef ACC_DW
#pragma unroll
  for (int off = 1; off < 64; off <<= 1)
    t += __shfl_xor(t, off, 64);
  if (l == 0) {
    red[wv * 2]     = valid ? (lse - t) : 0.f;
    red[wv * 2 + 1] = valid ? lse : 0.f;
  }
  __syncthreads();
  if (threadIdx.x == 0) {
    blk_part[blockIdx.x * 2]     = red[0] + red[2] + red[4] + red[6];
    blk_part[blockIdx.x * 2 + 1] = red[1] + red[3] + red[5] + red[7];
  }
}

// ------------- final single-block reduce -------
__global__ __launch_bounds__(256) void k_final(const float* __restrict__ bp,
                                               float* __restrict__ out) {
  __shared__ float ra[4], rb[4];
  float a = 0.f, b = 0.f;
  for (int i = threadIdx.x; i < N_ROWS / 4; i += 256) {
    a += bp[i * 2];
    b += bp[i * 2 + 1];
  }
#pragma unroll
  for (int off = 1; off < 64; off <<= 1) {
    a += __shfl_xor(a, off, 64);
    b += __shfl_xor(b, off, 64);
  }
  if ((threadIdx.x & 63) == 0) { ra[threadIdx.x >> 6] = a; rb[threadIdx.x >> 6] = b; }
  __syncthreads();
  if (threadIdx.x == 0) {
    out[0] = ra[0] + ra[1] + ra[2] + ra[3];
    out[1] = rb[0] + rb[1] + rb[2] + rb[3];
  }
}

extern "C" void kernel_launch(void* const* d_in, const int* in_sizes, int n_in,
                              void* d_out, int out_size, void* d_ws, size_t ws_size,
                              hipStream_t stream) {
  const float* x = (const float*)d_in[0];
  const float* w = (const float*)d_in[1];
  const int* target = (const int*)d_in[2];
  float* out = (float*)d_out;

  char* ws = (char*)d_ws;
  // ws layout:
  //   x8       : 4096*1024   =  4,194,304
  //   wT8      : 32000*1024  = 32,768,000
  //   m_part   : 4096*250*4  =  4,096,000
  //   s_part   : 4096*250*4  =  4,096,000
  //   blk_part : 1024*2*4    =      8,192
  unsigned char* x8 = (unsigned char*)ws;
  unsigned char* wT8 = (unsigned char*)(ws + 4194304);
  float* m_part = (float*)(ws + 4194304 + 32768000);
  float* s_part = (float*)(ws + 4194304 + 32768000 + 4096000);
  float* blk_part = (float*)(ws + 4194304 + 32768000 + 4096000 + 4096000);

  k_prep<<<dim3(XB8 + (V_DIM / 64) * (H_DIM / 128)), 256, 0, stream>>>(x, w, x8, wT8);
  k_gemm_lse<<<dim3(RT_NUM, CT_NUM), 256, 0, stream>>>(x8, wT8, m_part, s_part);
  k_combine<<<dim3(N_ROWS / 4), 256, 0, stream>>>(x, wT8, target, m_part, s_part, blk_part);
  k_final<<<dim3(1), 256, 0, stream>>>(blk_part, out);
}

// Round 6
// 451.737 us; speedup vs baseline: 1.9665x; 1.9665x over previous
//
#include <hip/hip_runtime.h>
#include <hip/hip_bf16.h>

typedef float f32x4 __attribute__((ext_vector_type(4)));
typedef int i32x4v __attribute__((ext_vector_type(4)));
typedef int i32x8v __attribute__((ext_vector_type(8)));

#define IGNORE_INDEX (-100)
#define N_ROWS 4096
#define H_DIM  1024
#define V_DIM  32000

#define BM 128
#define BN 128
#define BK 128                 /* fp8 elements = bytes */
#define CT_NUM (V_DIM / BN)    /* 250 */
#define RT_NUM (N_ROWS / BM)   /* 32 */
#define SCALE1 0x7f7f7f7f      /* 4x e8m0 = 127 -> x1.0 */

// ---------- fused prep: cast x -> fp8 (blocks < XB8) + transpose-cast w ----------
#define XB8 (N_ROWS * H_DIM / (256 * 16))  /* 1024 */
__global__ __launch_bounds__(256) void k_prep(const float* __restrict__ x,
                                              const float* __restrict__ w,
                                              unsigned char* __restrict__ x8,
                                              unsigned char* __restrict__ wT8) {
  __shared__ float tile[128][65];
  const int t = threadIdx.x;
  if (blockIdx.x < XB8) {
    size_t i = ((size_t)blockIdx.x * 256 + t) * 16;
    const float4* xp = (const float4*)(x + i);
    float4 f0 = xp[0], f1 = xp[1], f2 = xp[2], f3 = xp[3];
    int4 o;
    int r;
    r = __builtin_amdgcn_cvt_pk_fp8_f32(f0.x, f0.y, 0, false);
    r = __builtin_amdgcn_cvt_pk_fp8_f32(f0.z, f0.w, r, true);
    o.x = r;
    r = __builtin_amdgcn_cvt_pk_fp8_f32(f1.x, f1.y, 0, false);
    r = __builtin_amdgcn_cvt_pk_fp8_f32(f1.z, f1.w, r, true);
    o.y = r;
    r = __builtin_amdgcn_cvt_pk_fp8_f32(f2.x, f2.y, 0, false);
    r = __builtin_amdgcn_cvt_pk_fp8_f32(f2.z, f2.w, r, true);
    o.z = r;
    r = __builtin_amdgcn_cvt_pk_fp8_f32(f3.x, f3.y, 0, false);
    r = __builtin_amdgcn_cvt_pk_fp8_f32(f3.z, f3.w, r, true);
    o.w = r;
    *(int4*)(x8 + i) = o;
    return;
  }
  const int b = blockIdx.x - XB8;
  const int v0 = (b % (V_DIM / 64)) * 64;
  const int k0 = (b / (V_DIM / 64)) * 128;
  {
    const int vq = t & 15;    // float4 index (16 x 4 = 64 floats/row)
    const int kr = t >> 4;    // 0..15
#pragma unroll
    for (int p = 0; p < 128; p += 16) {
      float4 v = *(const float4*)(w + (size_t)(k0 + kr + p) * V_DIM + v0 + vq * 4);
      tile[kr + p][vq * 4 + 0] = v.x;
      tile[kr + p][vq * 4 + 1] = v.y;
      tile[kr + p][vq * 4 + 2] = v.z;
      tile[kr + p][vq * 4 + 3] = v.w;
    }
  }
  __syncthreads();
  {
    const int vr = t >> 2;    // 0..63
    const int kq2 = t & 3;
#pragma unroll
    for (int h = 0; h < 2; ++h) {
      const int d4 = kq2 + h * 4;   // int4 index within 128B k-run
      int4 o;
      int r;
#pragma unroll
      for (int d = 0; d < 4; ++d) {
        r = __builtin_amdgcn_cvt_pk_fp8_f32(tile[d4 * 16 + d * 4 + 0][vr],
                                            tile[d4 * 16 + d * 4 + 1][vr], 0, false);
        r = __builtin_amdgcn_cvt_pk_fp8_f32(tile[d4 * 16 + d * 4 + 2][vr],
                                            tile[d4 * 16 + d * 4 + 3][vr], r, true);
        ((int*)&o)[d] = r;
      }
      *(int4*)(wT8 + (size_t)(v0 + vr) * H_DIM + k0 + d4 * 16) = o;
    }
  }
}

// ------------- fused MX-fp8 GEMM tile + per-row max/sumexp partials -------------
// LDS layout per operand (16KB): 16B slot s holds (row = s>>3, chunk c where
// chunk-position (s&7) = c ^ (row&7)).  Epilogue max/sum buffers UNION into
// sA (dead after K-loop) -> LDS exactly 32768 B -> 5 blocks/CU.
// NOTE: no min-waves in launch_bounds — (256,5) forced VGPR 100->48 and
// spilled the accumulator (R5: WRITE_SIZE x160, GEMM 253->697us).
__global__ __launch_bounds__(256) void k_gemm_lse(const unsigned char* __restrict__ A,
                                                  const unsigned char* __restrict__ Bt,
                                                  float* __restrict__ m_part,
                                                  float* __restrict__ s_part) {
  __shared__ __align__(16) unsigned char sA[BM * BK];
  __shared__ __align__(16) unsigned char sB[BN * BK];
  float* maxbuf = (float*)sA;            // [BM][2], alias: sA dead post-loop
  float* sumbuf = (float*)(sA + 2048);   // [BM][2]

  const int tid = threadIdx.x;
  const int rt = blockIdx.x;   // fast dim -> per-XCD A stays hot
  const int ct = blockIdx.y;
  const int m0 = rt * BM;
  const int n0 = ct * BN;

  const int w = tid >> 6;
  const int l = tid & 63;
  const int wr = w >> 1, wc = w & 1;
  const int quad = l >> 4, lc = l & 15;

  f32x4 acc[4][4];
#pragma unroll
  for (int i = 0; i < 4; ++i)
#pragma unroll
    for (int j = 0; j < 4; ++j)
      acc[i][j] = (f32x4){0.f, 0.f, 0.f, 0.f};

  // staging addresses (issue i adds 32 rows / 4096 LDS bytes)
  const int srow = tid >> 3;                               // 0..31
  const int scol = ((tid & 7) ^ ((tid >> 3) & 7)) * 16;    // swizzled 16B chunk
  const unsigned char* ga = A + (size_t)(m0 + srow) * H_DIM + scol;
  const unsigned char* gb = Bt + (size_t)(n0 + srow) * H_DIM + scol;
  unsigned char* da = sA + tid * 16;
  unsigned char* db = sB + tid * 16;

  // fragment read offsets
  const int base_r = lc * 128;
  const int sw0 = ((quad * 2) ^ (lc & 7)) * 16;
  const int sw1 = ((quad * 2 + 1) ^ (lc & 7)) * 16;

  for (int kt = 0; kt < H_DIM / BK; ++kt) {
    __syncthreads();  // previous iter's ds_reads done before overwrite
#pragma unroll
    for (int i = 0; i < 4; ++i) {
      __builtin_amdgcn_global_load_lds(
          (const __attribute__((address_space(1))) void*)(ga + (size_t)i * 32 * H_DIM),
          (__attribute__((address_space(3))) void*)(da + i * 4096), 16, 0, 0);
      __builtin_amdgcn_global_load_lds(
          (const __attribute__((address_space(1))) void*)(gb + (size_t)i * 32 * H_DIM),
          (__attribute__((address_space(3))) void*)(db + i * 4096), 16, 0, 0);
    }
    ga += BK; gb += BK;
    __syncthreads();  // drains vmcnt for all waves

    i32x8v a_frag[4], b_frag[4];
#pragma unroll
    for (int i = 0; i < 4; ++i) {
      const unsigned char* p = sA + (wr * 4 + i) * 2048 + base_r;
      i32x4v lo = *(const i32x4v*)(p + sw0);
      i32x4v hi = *(const i32x4v*)(p + sw1);
      a_frag[i] = __builtin_shufflevector(lo, hi, 0, 1, 2, 3, 4, 5, 6, 7);
    }
#pragma unroll
    for (int j = 0; j < 4; ++j) {
      const unsigned char* p = sB + (wc * 4 + j) * 2048 + base_r;
      i32x4v lo = *(const i32x4v*)(p + sw0);
      i32x4v hi = *(const i32x4v*)(p + sw1);
      b_frag[j] = __builtin_shufflevector(lo, hi, 0, 1, 2, 3, 4, 5, 6, 7);
    }
#pragma unroll
    for (int i = 0; i < 4; ++i)
#pragma unroll
      for (int j = 0; j < 4; ++j)
        acc[i][j] = __builtin_amdgcn_mfma_scale_f32_16x16x128_f8f6f4(
            a_frag[i], b_frag[j], acc[i][j], 0, 0, 0, SCALE1, 0, SCALE1);
  }

  // C/D layout (shape-determined): col = lane&15, row = quad*4 + reg.
  float rmax[4][4];
#pragma unroll
  for (int i = 0; i < 4; ++i)
#pragma unroll
    for (int r = 0; r < 4; ++r) {
      float mx = fmaxf(fmaxf(acc[i][0][r], acc[i][1][r]),
                       fmaxf(acc[i][2][r], acc[i][3][r]));
#pragma unroll
      for (int off = 1; off < 16; off <<= 1)
        mx = fmaxf(mx, __shfl_xor(mx, off, 64));
      rmax[i][r] = mx;
    }
  __syncthreads();  // all waves past final ds_reads; sA now safe to alias
  if (lc == 0) {
#pragma unroll
    for (int i = 0; i < 4; ++i)
#pragma unroll
      for (int r = 0; r < 4; ++r)
        maxbuf[(wr * 64 + i * 16 + quad * 4 + r) * 2 + wc] = rmax[i][r];
  }
  __syncthreads();
  float rowmax[4][4];
#pragma unroll
  for (int i = 0; i < 4; ++i)
#pragma unroll
    for (int r = 0; r < 4; ++r) {
      int row = wr * 64 + i * 16 + quad * 4 + r;
      rowmax[i][r] = fmaxf(maxbuf[row * 2], maxbuf[row * 2 + 1]);
    }
#pragma unroll
  for (int i = 0; i < 4; ++i)
#pragma unroll
    for (int r = 0; r < 4; ++r) {
      float s = __expf(acc[i][0][r] - rowmax[i][r]) + __expf(acc[i][1][r] - rowmax[i][r]) +
                __expf(acc[i][2][r] - rowmax[i][r]) + __expf(acc[i][3][r] - rowmax[i][r]);
#pragma unroll
      for (int off = 1; off < 16; off <<= 1)
        s += __shfl_xor(s, off, 64);
      if (lc == 0) sumbuf[(wr * 64 + i * 16 + quad * 4 + r) * 2 + wc] = s;
    }
  __syncthreads();
  if (wc == 0 && lc == 0) {
#pragma unroll
    for (int i = 0; i < 4; ++i)
#pragma unroll
      for (int r = 0; r < 4; ++r) {
        int row = wr * 64 + i * 16 + quad * 4 + r;
        size_t idx = (size_t)(m0 + row) * CT_NUM + ct;
        m_part[idx] = rowmax[i][r];
        s_part[idx] = sumbuf[row * 2] + sumbuf[row * 2 + 1];
      }
  }
}

// ------------- combine partials + target logit -> per-block partial sums ----
__global__ __launch_bounds__(256) void k_combine(const float* __restrict__ x,
                                                 const unsigned char* __restrict__ wT8,
                                                 const int* __restrict__ target,
                                                 const float* __restrict__ m_part,
                                                 const float* __restrict__ s_part,
                                                 float* __restrict__ blk_part) {
  __shared__ float red[8];
  const int wv = threadIdx.x >> 6;
  const int row = blockIdx.x * 4 + wv;  // one wave per row
  const int l = threadIdx.x & 63;
  float m = -INFINITY, s = 0.f;
  for (int ctb = l; ctb < CT_NUM; ctb += 64) {
    float mj = m_part[(size_t)row * CT_NUM + ctb];
    float sj = s_part[(size_t)row * CT_NUM + ctb];
    float M = fmaxf(m, mj);
    s = s * __expf(m - M) + sj * __expf(mj - M);
    m = M;
  }
#pragma unroll
  for (int off = 1; off < 64; off <<= 1) {
    float mo = __shfl_xor(m, off, 64);
    float so = __shfl_xor(s, off, 64);
    float M = fmaxf(m, mo);
    s = s * __expf(m - M) + so * __expf(mo - M);
    m = M;
  }
  float lse = m + logf(s);
  int tgt = target[row];
  bool valid = (tgt != IGNORE_INDEX);
  int st = valid ? tgt : 0;
  // target logit: x[row] fp32 . wT8[st] fp8 (16 bytes per lane)
  const float* xr = x + (size_t)row * H_DIM + l * 16;
  int4 wv4 = *(const int4*)(wT8 + (size_t)st * H_DIM + l * 16);
  float t = 0.f;
#define ACC_DW(dw, base)                                              \
  t += xr[base + 0] * __builtin_amdgcn_cvt_f32_fp8(dw, 0);            \
  t += xr[base + 1] * __builtin_amdgcn_cvt_f32_fp8(dw, 1);            \
  t += xr[base + 2] * __builtin_amdgcn_cvt_f32_fp8(dw, 2);            \
  t += xr[base + 3] * __builtin_amdgcn_cvt_f32_fp8(dw, 3);
  ACC_DW(wv4.x, 0)
  ACC_DW(wv4.y, 4)
  ACC_DW(wv4.z, 8)
  ACC_DW(wv4.w, 12)
#undef ACC_DW
#pragma unroll
  for (int off = 1; off < 64; off <<= 1)
    t += __shfl_xor(t, off, 64);
  if (l == 0) {
    red[wv * 2]     = valid ? (lse - t) : 0.f;
    red[wv * 2 + 1] = valid ? lse : 0.f;
  }
  __syncthreads();
  if (threadIdx.x == 0) {
    blk_part[blockIdx.x * 2]     = red[0] + red[2] + red[4] + red[6];
    blk_part[blockIdx.x * 2 + 1] = red[1] + red[3] + red[5] + red[7];
  }
}

// ------------- final single-block reduce -------
__global__ __launch_bounds__(256) void k_final(const float* __restrict__ bp,
                                               float* __restrict__ out) {
  __shared__ float ra[4], rb[4];
  float a = 0.f, b = 0.f;
  for (int i = threadIdx.x; i < N_ROWS / 4; i += 256) {
    a += bp[i * 2];
    b += bp[i * 2 + 1];
  }
#pragma unroll
  for (int off = 1; off < 64; off <<= 1) {
    a += __shfl_xor(a, off, 64);
    b += __shfl_xor(b, off, 64);
  }
  if ((threadIdx.x & 63) == 0) { ra[threadIdx.x >> 6] = a; rb[threadIdx.x >> 6] = b; }
  __syncthreads();
  if (threadIdx.x == 0) {
    out[0] = ra[0] + ra[1] + ra[2] + ra[3];
    out[1] = rb[0] + rb[1] + rb[2] + rb[3];
  }
}

extern "C" void kernel_launch(void* const* d_in, const int* in_sizes, int n_in,
                              void* d_out, int out_size, void* d_ws, size_t ws_size,
                              hipStream_t stream) {
  const float* x = (const float*)d_in[0];
  const float* w = (const float*)d_in[1];
  const int* target = (const int*)d_in[2];
  float* out = (float*)d_out;

  char* ws = (char*)d_ws;
  // ws layout:
  //   x8       : 4096*1024   =  4,194,304
  //   wT8      : 32000*1024  = 32,768,000
  //   m_part   : 4096*250*4  =  4,096,000
  //   s_part   : 4096*250*4  =  4,096,000
  //   blk_part : 1024*2*4    =      8,192
  unsigned char* x8 = (unsigned char*)ws;
  unsigned char* wT8 = (unsigned char*)(ws + 4194304);
  float* m_part = (float*)(ws + 4194304 + 32768000);
  float* s_part = (float*)(ws + 4194304 + 32768000 + 4096000);
  float* blk_part = (float*)(ws + 4194304 + 32768000 + 4096000 + 4096000);

  k_prep<<<dim3(XB8 + (V_DIM / 64) * (H_DIM / 128)), 256, 0, stream>>>(x, w, x8, wT8);
  k_gemm_lse<<<dim3(RT_NUM, CT_NUM), 256, 0, stream>>>(x8, wT8, m_part, s_part);
  k_combine<<<dim3(N_ROWS / 4), 256, 0, stream>>>(x, wT8, target, m_part, s_part, blk_part);
  k_final<<<dim3(1), 256, 0, stream>>>(blk_part, out);
}

// Round 7
// 434.218 us; speedup vs baseline: 2.0458x; 1.0403x over previous
//
#include <hip/hip_runtime.h>
#include <hip/hip_bf16.h>

typedef float f32x4 __attribute__((ext_vector_type(4)));
typedef int i32x4v __attribute__((ext_vector_type(4)));
typedef int i32x8v __attribute__((ext_vector_type(8)));

#define IGNORE_INDEX (-100)
#define N_ROWS 4096
#define H_DIM  1024
#define V_DIM  32000

#define BM 128
#define BN 128
#define BK 128                 /* fp8 elements = bytes */
#define CT_NUM (V_DIM / BN)    /* 250 */
#define RT_NUM (N_ROWS / BM)   /* 32 */
#define SCALE1 0x7f7f7f7f      /* 4x e8m0 = 127 -> x1.0 */

// ---------- fused prep: cast x -> fp8 (blocks < XB8) + transpose-cast w ----------
#define XB8 (N_ROWS * H_DIM / (256 * 16))  /* 1024 */
__global__ __launch_bounds__(256) void k_prep(const float* __restrict__ x,
                                              const float* __restrict__ w,
                                              unsigned char* __restrict__ x8,
                                              unsigned char* __restrict__ wT8) {
  __shared__ float tile[128][65];
  const int t = threadIdx.x;
  if (blockIdx.x < XB8) {
    size_t i = ((size_t)blockIdx.x * 256 + t) * 16;
    const float4* xp = (const float4*)(x + i);
    float4 f0 = xp[0], f1 = xp[1], f2 = xp[2], f3 = xp[3];
    int4 o;
    int r;
    r = __builtin_amdgcn_cvt_pk_fp8_f32(f0.x, f0.y, 0, false);
    r = __builtin_amdgcn_cvt_pk_fp8_f32(f0.z, f0.w, r, true);
    o.x = r;
    r = __builtin_amdgcn_cvt_pk_fp8_f32(f1.x, f1.y, 0, false);
    r = __builtin_amdgcn_cvt_pk_fp8_f32(f1.z, f1.w, r, true);
    o.y = r;
    r = __builtin_amdgcn_cvt_pk_fp8_f32(f2.x, f2.y, 0, false);
    r = __builtin_amdgcn_cvt_pk_fp8_f32(f2.z, f2.w, r, true);
    o.z = r;
    r = __builtin_amdgcn_cvt_pk_fp8_f32(f3.x, f3.y, 0, false);
    r = __builtin_amdgcn_cvt_pk_fp8_f32(f3.z, f3.w, r, true);
    o.w = r;
    *(int4*)(x8 + i) = o;
    return;
  }
  const int b = blockIdx.x - XB8;
  const int v0 = (b % (V_DIM / 64)) * 64;
  const int k0 = (b / (V_DIM / 64)) * 128;
  {
    const int vq = t & 15;    // float4 index (16 x 4 = 64 floats/row)
    const int kr = t >> 4;    // 0..15
#pragma unroll
    for (int p = 0; p < 128; p += 16) {
      float4 v = *(const float4*)(w + (size_t)(k0 + kr + p) * V_DIM + v0 + vq * 4);
      tile[kr + p][vq * 4 + 0] = v.x;
      tile[kr + p][vq * 4 + 1] = v.y;
      tile[kr + p][vq * 4 + 2] = v.z;
      tile[kr + p][vq * 4 + 3] = v.w;
    }
  }
  __syncthreads();
  {
    const int vr = t >> 2;    // 0..63
    const int kq2 = t & 3;
#pragma unroll
    for (int h = 0; h < 2; ++h) {
      const int d4 = kq2 + h * 4;   // int4 index within 128B k-run
      int4 o;
      int r;
#pragma unroll
      for (int d = 0; d < 4; ++d) {
        r = __builtin_amdgcn_cvt_pk_fp8_f32(tile[d4 * 16 + d * 4 + 0][vr],
                                            tile[d4 * 16 + d * 4 + 1][vr], 0, false);
        r = __builtin_amdgcn_cvt_pk_fp8_f32(tile[d4 * 16 + d * 4 + 2][vr],
                                            tile[d4 * 16 + d * 4 + 3][vr], r, true);
        ((int*)&o)[d] = r;
      }
      *(int4*)(wT8 + (size_t)(v0 + vr) * H_DIM + k0 + d4 * 16) = o;
    }
  }
}

// ------------- fused MX-fp8 GEMM + per-row max/sumexp, DOUBLE-BUFFERED -------------
// K-loop restructure: prefetch tile k+1 is issued AFTER the barrier of iter k,
// so the vmcnt drain inside __syncthreads() at iter k+1 targets loads that are
// one full compute phase (~550 cyc, mostly L2-hit latency) old -> near-free.
// Race-free: the barrier at iter k guarantees all waves finished iter k-1's
// ds_reads of buf[(k+1)&1] before we overwrite it.
// LDS: 2 x (16K A + 16K B) = 64 KB -> 2 blocks/CU (trade occupancy for drain).
__global__ __launch_bounds__(256) void k_gemm_lse(const unsigned char* __restrict__ A,
                                                  const unsigned char* __restrict__ Bt,
                                                  float* __restrict__ m_part,
                                                  float* __restrict__ s_part) {
  __shared__ __align__(16) unsigned char sMem[2][2][BM * BK];  // [buf][A=0/B=1]
  float* maxbuf = (float*)&sMem[0][0][0];            // alias: dead after K-loop
  float* sumbuf = (float*)&sMem[0][0][2048];

  const int tid = threadIdx.x;
  const int rt = blockIdx.x;   // fast dim -> per-XCD A stays hot
  const int ct = blockIdx.y;
  const int m0 = rt * BM;
  const int n0 = ct * BN;

  const int w = tid >> 6;
  const int l = tid & 63;
  const int wr = w >> 1, wc = w & 1;
  const int quad = l >> 4, lc = l & 15;

  f32x4 acc[4][4];
#pragma unroll
  for (int i = 0; i < 4; ++i)
#pragma unroll
    for (int j = 0; j < 4; ++j)
      acc[i][j] = (f32x4){0.f, 0.f, 0.f, 0.f};

  // staging addresses (issue i adds 32 rows / 4096 LDS bytes)
  const int srow = tid >> 3;                               // 0..31
  const int scol = ((tid & 7) ^ ((tid >> 3) & 7)) * 16;    // swizzled 16B chunk
  const unsigned char* ga = A + (size_t)(m0 + srow) * H_DIM + scol;
  const unsigned char* gb = Bt + (size_t)(n0 + srow) * H_DIM + scol;
  const int dOff = tid * 16;

  // fragment read offsets
  const int base_r = lc * 128;
  const int sw0 = ((quad * 2) ^ (lc & 7)) * 16;
  const int sw1 = ((quad * 2 + 1) ^ (lc & 7)) * 16;

#define ISSUE_TILE(buf)                                                          \
  do {                                                                           \
    unsigned char* da_ = &sMem[buf][0][dOff];                                    \
    unsigned char* db_ = &sMem[buf][1][dOff];                                    \
    _Pragma("unroll")                                                            \
    for (int i_ = 0; i_ < 4; ++i_) {                                             \
      __builtin_amdgcn_global_load_lds(                                          \
          (const __attribute__((address_space(1))) void*)(ga + (size_t)i_ * 32 * H_DIM), \
          (__attribute__((address_space(3))) void*)(da_ + i_ * 4096), 16, 0, 0); \
      __builtin_amdgcn_global_load_lds(                                          \
          (const __attribute__((address_space(1))) void*)(gb + (size_t)i_ * 32 * H_DIM), \
          (__attribute__((address_space(3))) void*)(db_ + i_ * 4096), 16, 0, 0); \
    }                                                                            \
    ga += BK;                                                                    \
    gb += BK;                                                                    \
  } while (0)

  ISSUE_TILE(0);  // cold prologue load, tile 0

#pragma unroll
  for (int kt = 0; kt < H_DIM / BK; ++kt) {
    __syncthreads();  // drains tile-kt loads (aged 1 compute phase for kt>0);
                      // guarantees all waves done reading buf[(kt+1)&1]
    if (kt < H_DIM / BK - 1) ISSUE_TILE((kt + 1) & 1);

    const unsigned char* bufA = &sMem[kt & 1][0][0];
    const unsigned char* bufB = &sMem[kt & 1][1][0];
    i32x8v a_frag[4], b_frag[4];
#pragma unroll
    for (int i = 0; i < 4; ++i) {
      const unsigned char* p = bufA + (wr * 4 + i) * 2048 + base_r;
      i32x4v lo = *(const i32x4v*)(p + sw0);
      i32x4v hi = *(const i32x4v*)(p + sw1);
      a_frag[i] = __builtin_shufflevector(lo, hi, 0, 1, 2, 3, 4, 5, 6, 7);
    }
#pragma unroll
    for (int j = 0; j < 4; ++j) {
      const unsigned char* p = bufB + (wc * 4 + j) * 2048 + base_r;
      i32x4v lo = *(const i32x4v*)(p + sw0);
      i32x4v hi = *(const i32x4v*)(p + sw1);
      b_frag[j] = __builtin_shufflevector(lo, hi, 0, 1, 2, 3, 4, 5, 6, 7);
    }
#pragma unroll
    for (int i = 0; i < 4; ++i)
#pragma unroll
      for (int j = 0; j < 4; ++j)
        acc[i][j] = __builtin_amdgcn_mfma_scale_f32_16x16x128_f8f6f4(
            a_frag[i], b_frag[j], acc[i][j], 0, 0, 0, SCALE1, 0, SCALE1);
  }
#undef ISSUE_TILE

  // C/D layout (shape-determined): col = lane&15, row = quad*4 + reg.
  float rmax[4][4];
#pragma unroll
  for (int i = 0; i < 4; ++i)
#pragma unroll
    for (int r = 0; r < 4; ++r) {
      float mx = fmaxf(fmaxf(acc[i][0][r], acc[i][1][r]),
                       fmaxf(acc[i][2][r], acc[i][3][r]));
#pragma unroll
      for (int off = 1; off < 16; off <<= 1)
        mx = fmaxf(mx, __shfl_xor(mx, off, 64));
      rmax[i][r] = mx;
    }
  __syncthreads();  // all waves past final ds_reads; sMem safe to alias
  if (lc == 0) {
#pragma unroll
    for (int i = 0; i < 4; ++i)
#pragma unroll
      for (int r = 0; r < 4; ++r)
        maxbuf[(wr * 64 + i * 16 + quad * 4 + r) * 2 + wc] = rmax[i][r];
  }
  __syncthreads();
  float rowmax[4][4];
#pragma unroll
  for (int i = 0; i < 4; ++i)
#pragma unroll
    for (int r = 0; r < 4; ++r) {
      int row = wr * 64 + i * 16 + quad * 4 + r;
      rowmax[i][r] = fmaxf(maxbuf[row * 2], maxbuf[row * 2 + 1]);
    }
#pragma unroll
  for (int i = 0; i < 4; ++i)
#pragma unroll
    for (int r = 0; r < 4; ++r) {
      float s = __expf(acc[i][0][r] - rowmax[i][r]) + __expf(acc[i][1][r] - rowmax[i][r]) +
                __expf(acc[i][2][r] - rowmax[i][r]) + __expf(acc[i][3][r] - rowmax[i][r]);
#pragma unroll
      for (int off = 1; off < 16; off <<= 1)
        s += __shfl_xor(s, off, 64);
      if (lc == 0) sumbuf[(wr * 64 + i * 16 + quad * 4 + r) * 2 + wc] = s;
    }
  __syncthreads();
  if (wc == 0 && lc == 0) {
#pragma unroll
    for (int i = 0; i < 4; ++i)
#pragma unroll
      for (int r = 0; r < 4; ++r) {
        int row = wr * 64 + i * 16 + quad * 4 + r;
        size_t idx = (size_t)(m0 + row) * CT_NUM + ct;
        m_part[idx] = rowmax[i][r];
        s_part[idx] = sumbuf[row * 2] + sumbuf[row * 2 + 1];
      }
  }
}

// ------------- combine partials + target logit -> per-block partial sums ----
__global__ __launch_bounds__(256) void k_combine(const float* __restrict__ x,
                                                 const unsigned char* __restrict__ wT8,
                                                 const int* __restrict__ target,
                                                 const float* __restrict__ m_part,
                                                 const float* __restrict__ s_part,
                                                 float* __restrict__ blk_part) {
  __shared__ float red[8];
  const int wv = threadIdx.x >> 6;
  const int row = blockIdx.x * 4 + wv;  // one wave per row
  const int l = threadIdx.x & 63;
  float m = -INFINITY, s = 0.f;
  for (int ctb = l; ctb < CT_NUM; ctb += 64) {
    float mj = m_part[(size_t)row * CT_NUM + ctb];
    float sj = s_part[(size_t)row * CT_NUM + ctb];
    float M = fmaxf(m, mj);
    s = s * __expf(m - M) + sj * __expf(mj - M);
    m = M;
  }
#pragma unroll
  for (int off = 1; off < 64; off <<= 1) {
    float mo = __shfl_xor(m, off, 64);
    float so = __shfl_xor(s, off, 64);
    float M = fmaxf(m, mo);
    s = s * __expf(m - M) + so * __expf(mo - M);
    m = M;
  }
  float lse = m + logf(s);
  int tgt = target[row];
  bool valid = (tgt != IGNORE_INDEX);
  int st = valid ? tgt : 0;
  // target logit: x[row] fp32 . wT8[st] fp8 (16 bytes per lane)
  const float* xr = x + (size_t)row * H_DIM + l * 16;
  int4 wv4 = *(const int4*)(wT8 + (size_t)st * H_DIM + l * 16);
  float t = 0.f;
#define ACC_DW(dw, base)                                              \
  t += xr[base + 0] * __builtin_amdgcn_cvt_f32_fp8(dw, 0);            \
  t += xr[base + 1] * __builtin_amdgcn_cvt_f32_fp8(dw, 1);            \
  t += xr[base + 2] * __builtin_amdgcn_cvt_f32_fp8(dw, 2);            \
  t += xr[base + 3] * __builtin_amdgcn_cvt_f32_fp8(dw, 3);
  ACC_DW(wv4.x, 0)
  ACC_DW(wv4.y, 4)
  ACC_DW(wv4.z, 8)
  ACC_DW(wv4.w, 12)
#undef ACC_DW
#pragma unroll
  for (int off = 1; off < 64; off <<= 1)
    t += __shfl_xor(t, off, 64);
  if (l == 0) {
    red[wv * 2]     = valid ? (lse - t) : 0.f;
    red[wv * 2 + 1] = valid ? lse : 0.f;
  }
  __syncthreads();
  if (threadIdx.x == 0) {
    blk_part[blockIdx.x * 2]     = red[0] + red[2] + red[4] + red[6];
    blk_part[blockIdx.x * 2 + 1] = red[1] + red[3] + red[5] + red[7];
  }
}

// ------------- final single-block reduce -------
__global__ __launch_bounds__(256) void k_final(const float* __restrict__ bp,
                                               float* __restrict__ out) {
  __shared__ float ra[4], rb[4];
  float a = 0.f, b = 0.f;
  for (int i = threadIdx.x; i < N_ROWS / 4; i += 256) {
    a += bp[i * 2];
    b += bp[i * 2 + 1];
  }
#pragma unroll
  for (int off = 1; off < 64; off <<= 1) {
    a += __shfl_xor(a, off, 64);
    b += __shfl_xor(b, off, 64);
  }
  if ((threadIdx.x & 63) == 0) { ra[threadIdx.x >> 6] = a; rb[threadIdx.x >> 6] = b; }
  __syncthreads();
  if (threadIdx.x == 0) {
    out[0] = ra[0] + ra[1] + ra[2] + ra[3];
    out[1] = rb[0] + rb[1] + rb[2] + rb[3];
  }
}

extern "C" void kernel_launch(void* const* d_in, const int* in_sizes, int n_in,
                              void* d_out, int out_size, void* d_ws, size_t ws_size,
                              hipStream_t stream) {
  const float* x = (const float*)d_in[0];
  const float* w = (const float*)d_in[1];
  const int* target = (const int*)d_in[2];
  float* out = (float*)d_out;

  char* ws = (char*)d_ws;
  // ws layout:
  //   x8       : 4096*1024   =  4,194,304
  //   wT8      : 32000*1024  = 32,768,000
  //   m_part   : 4096*250*4  =  4,096,000
  //   s_part   : 4096*250*4  =  4,096,000
  //   blk_part : 1024*2*4    =      8,192
  unsigned char* x8 = (unsigned char*)ws;
  unsigned char* wT8 = (unsigned char*)(ws + 4194304);
  float* m_part = (float*)(ws + 4194304 + 32768000);
  float* s_part = (float*)(ws + 4194304 + 32768000 + 4096000);
  float* blk_part = (float*)(ws + 4194304 + 32768000 + 4096000 + 4096000);

  k_prep<<<dim3(XB8 + (V_DIM / 64) * (H_DIM / 128)), 256, 0, stream>>>(x, w, x8, wT8);
  k_gemm_lse<<<dim3(RT_NUM, CT_NUM), 256, 0, stream>>>(x8, wT8, m_part, s_part);
  k_combine<<<dim3(N_ROWS / 4), 256, 0, stream>>>(x, wT8, target, m_part, s_part, blk_part);
  k_final<<<dim3(1), 256, 0, stream>>>(blk_part, out);
}